// Round 1
// baseline (192.437 us; speedup 1.0000x reference)
//
#include <hip/hip_runtime.h>
#include <hip/hip_bf16.h>

typedef __attribute__((ext_vector_type(8))) short short8;
typedef __attribute__((ext_vector_type(4))) float floatx4;

// Binarize per torch 'det': ((t-0.5).sign()+1)/2 -> {0, 0.5, 1}
// Return bf16 bit pattern directly (0x0000 / 0x3F00 / 0x3F80) — no cvt needed.
__device__ __forceinline__ short bin_bf16s(float v) {
    float d = v - 0.5f;
    return (d > 0.f) ? (short)0x3F80 : ((d < 0.f) ? (short)0 : (short)0x3F00);
}
__device__ __forceinline__ float bin_f32(float v) {
    float d = v - 0.5f;
    return (d > 0.f) ? 1.f : ((d < 0.f) ? 0.f : 0.5f);
}

// Prep: binarize conv_w [120][120] fp32 -> bf16 panel [128][128] row-major
// (row = out-channel n, col = k), zero-padded, XOR-swizzled: byte ^= (n&7)<<4.
// Grid: 8 blocks x 256 threads; one 16B granule (8 bf16) per thread.
__global__ void prep_w(const float* __restrict__ w, unsigned short* __restrict__ wb) {
    int g  = blockIdx.x * 256 + threadIdx.x;  // 0..2047 granules
    int n  = g >> 4;                          // 0..127
    int gi = g & 15;                          // 0..15, k0 = gi*8
    int k0 = gi * 8;
    short8 v = {0, 0, 0, 0, 0, 0, 0, 0};
    if (n < 120 && gi < 15) {                 // 120 = 15*8 exactly
        const float* p = w + n * 120 + k0;    // 16B aligned (480 and 32 are mult of 16)
        floatx4 f0 = *(const floatx4*)p;
        floatx4 f1 = *(const floatx4*)(p + 4);
        #pragma unroll
        for (int j = 0; j < 4; ++j) { v[j] = bin_bf16s(f0[j]); v[4 + j] = bin_bf16s(f1[j]); }
    }
    int byte = (n * 256 + k0 * 2) ^ ((n & 7) << 4);   // swizzle keeps 16B alignment
    *(short8*)((char*)wb + byte) = v;
}

// Main: block = 256 thr (4 waves), each wave owns 32 rows (2 row-tiles of 16).
// Block covers 128 rows; grid = 262144/128 = 2048.
// LDS holds the swizzled bf16 W panel (32 KB). A streams from global.
__global__ __launch_bounds__(256) void bnn_main(
    const float* __restrict__ x, const unsigned short* __restrict__ wbs,
    const float* __restrict__ lin_w, float* __restrict__ out)
{
    __shared__ unsigned short W[16384];  // 32 KB, swizzled [128][128] bf16

    const int tid = threadIdx.x;
    // ws -> LDS, linear copy (panel already swizzled), 2048 float4 chunks
    {
        const floatx4* src = (const floatx4*)wbs;
        floatx4*       dst = (floatx4*)W;
        #pragma unroll
        for (int i = 0; i < 8; ++i) dst[tid + i * 256] = src[tid + i * 256];
    }
    __syncthreads();

    const int wave = tid >> 6;
    const int lane = tid & 63;
    const int cl   = lane & 15;   // fragment col (A: row; B: col; C: col)
    const int q    = lane >> 4;   // k-group / C row-group
    const long row0 = (long)blockIdx.x * 128 + (long)wave * 32;

    // lin_w binarized, per-lane col = t*16 + cl (pad cols -> 0)
    float lw[8];
    #pragma unroll
    for (int t = 0; t < 8; ++t) {
        int c = t * 16 + cl;
        lw[t] = (c < 120) ? bin_f32(lin_w[c]) : 0.f;
    }

    floatx4 acc[2][8];
    const floatx4 z4 = {0.f, 0.f, 0.f, 0.f};
    #pragma unroll
    for (int rt = 0; rt < 2; ++rt)
        #pragma unroll
        for (int t = 0; t < 8; ++t) acc[rt][t] = z4;

    const char* Wb = (const char*)W;
    const float* rp0 = x + (row0 + cl) * 120;        // row-tile 0, this lane's row
    const float* rp1 = x + (row0 + 16 + cl) * 120;   // row-tile 1

    #pragma unroll
    for (int s = 0; s < 4; ++s) {
        // A fragments: lane holds x_bin[row][s*32 + q*8 .. +8]. K=120 -> the
        // (s==3, q==3) group is entirely padding (k 120..127) -> zeros, no load.
        short8 af[2];
        #pragma unroll
        for (int rt = 0; rt < 2; ++rt) {
            short8 a = {0, 0, 0, 0, 0, 0, 0, 0};
            if (!(s == 3 && q == 3)) {
                const float* p = (rt == 0 ? rp0 : rp1) + s * 32 + q * 8;
                floatx4 f0 = *(const floatx4*)p;
                floatx4 f1 = *(const floatx4*)(p + 4);
                #pragma unroll
                for (int j = 0; j < 4; ++j) { a[j] = bin_bf16s(f0[j]); a[4 + j] = bin_bf16s(f1[j]); }
            }
            af[rt] = a;
        }
        #pragma unroll
        for (int t = 0; t < 8; ++t) {
            int n = t * 16 + cl;
            int byte = (n * 256 + (s * 32 + q * 8) * 2) ^ ((n & 7) << 4);
            short8 bf = *(const short8*)(Wb + byte);
            acc[0][t] = __builtin_amdgcn_mfma_f32_16x16x32_bf16(af[0], bf, acc[0][t], 0, 0, 0);
            acc[1][t] = __builtin_amdgcn_mfma_f32_16x16x32_bf16(af[1], bf, acc[1][t], 0, 0, 0);
        }
    }

    // Epilogue: y -> sb = (y>1 ? 1 : y==1 ? 0.5 : 0); out[row] = sum_col sb*lwb[col].
    // C layout: col = cl, row = q*4 + j. Reduce over the 16 lanes sharing q.
    #pragma unroll
    for (int rt = 0; rt < 2; ++rt) {
        float p4[4] = {0.f, 0.f, 0.f, 0.f};
        #pragma unroll
        for (int t = 0; t < 8; ++t)
            #pragma unroll
            for (int j = 0; j < 4; ++j) {
                float y  = acc[rt][t][j];
                float sb = (y > 1.f) ? 1.f : ((y == 1.f) ? 0.5f : 0.f);
                p4[j] += sb * lw[t];
            }
        #pragma unroll
        for (int m = 1; m <= 8; m <<= 1)
            #pragma unroll
            for (int j = 0; j < 4; ++j) p4[j] += __shfl_xor(p4[j], m, 64);
        if (cl == 0) {
            #pragma unroll
            for (int j = 0; j < 4; ++j)
                out[row0 + rt * 16 + q * 4 + j] = p4[j];
        }
    }
}

extern "C" void kernel_launch(void* const* d_in, const int* in_sizes, int n_in,
                              void* d_out, int out_size, void* d_ws, size_t ws_size,
                              hipStream_t stream) {
    const float* x      = (const float*)d_in[0];   // [262144,1,1,120] fp32
    const float* conv_w = (const float*)d_in[1];   // [120,1,1,120] fp32
    const float* lin_w  = (const float*)d_in[2];   // [1,120] fp32
    float*       out    = (float*)d_out;           // [262144,1] fp32
    unsigned short* wbs = (unsigned short*)d_ws;   // 32 KB swizzled bf16 W panel

    prep_w<<<dim3(8), dim3(256), 0, stream>>>(conv_w, wbs);

    const int B = in_sizes[0] / 120;               // 262144
    bnn_main<<<dim3(B / 128), dim3(256), 0, stream>>>(x, wbs, lin_w, out);
}